// Round 6
// baseline (420.112 us; speedup 1.0000x reference)
//
#include <hip/hip_runtime.h>
#include <hip/hip_bf16.h>

typedef __bf16  bf16x8 __attribute__((ext_vector_type(8)));
typedef float   floatx4 __attribute__((ext_vector_type(4)));

// ---------------- fused prep kernel ----------------
// blocks 0..511    : x NCHW fp32 -> xT bf16 NHWC + sq[b][hw] = sum_c x^2 (no atomics)
// blocks 512..1535 : prototypes -> wT bf16 [p][(kh*3+kw)*256+c], ps_sq[p]
__global__ __launch_bounds__(256) void prep_all(const float* __restrict__ x,
                                                const float* __restrict__ w,
                                                __hip_bfloat16* __restrict__ xT,
                                                __hip_bfloat16* __restrict__ wT,
                                                float* __restrict__ ps,
                                                float* __restrict__ sq) {
  __shared__ __align__(16) float shm[12740];   // x-path: tile[49][260]; w-path: 2560

  const int bid = blockIdx.x;
  const int tid = threadIdx.x;

  if (bid < 512) {
    // ---- x path: block = (b, 49-hw chunk) x all 256 c
    const int b = bid >> 4;
    const int hw0 = (bid & 15) * 49;
    float (*tile)[260] = (float(*)[260])shm;
    const float* xb = x + (long)b * 256 * 784 + hw0;
#pragma unroll
    for (int it = 0; it < 49; ++it) {          // 12544 elems, c-major runs of 49
      int flat = it * 256 + tid;
      int c = flat / 49, r = flat - c * 49;
      tile[r][c] = xb[c * 784 + r];
    }
    __syncthreads();
    // store: lane owns 4 consecutive c -> 512 B per wave-instruction
    const int c4 = (tid & 63) * 4;
    const int hwq = tid >> 6;
#pragma unroll
    for (int it = 0; it < 13; ++it) {
      int hw = it * 4 + hwq;
      if (hw < 49) {
        float4 tv = *(const float4*)&tile[hw][c4];
        __hip_bfloat16 h0 = __float2bfloat16(tv.x);
        __hip_bfloat16 h1 = __float2bfloat16(tv.y);
        __hip_bfloat16 h2 = __float2bfloat16(tv.z);
        __hip_bfloat16 h3 = __float2bfloat16(tv.w);
        ushort4 pk;
        pk.x = *(unsigned short*)&h0; pk.y = *(unsigned short*)&h1;
        pk.z = *(unsigned short*)&h2; pk.w = *(unsigned short*)&h3;
        *(ushort4*)&xT[((long)b * 784 + hw0 + hw) * 256 + c4] = pk;
      }
    }
    // fused sum of squares: 4 lanes per hw-row
    if (tid < 196) {
      const int r = tid >> 2, q = tid & 3;
      float s = 0.f;
#pragma unroll
      for (int cc = 0; cc < 64; ++cc) {
        float v = tile[r][q * 64 + cc];
        s += v * v;
      }
      s += __shfl_xor(s, 1);
      s += __shfl_xor(s, 2);
      if (q == 0) sq[b * 784 + hw0 + r] = s;
    }
  } else {
    // ---- w path
    const int p = bid - 512;
    float* wbuf = shm;            // 2304
    float* redw = shm + 2304;     // 256
    const float* src = w + (long)p * 2304;
#pragma unroll
    for (int r = 0; r < 9; ++r) wbuf[r * 256 + tid] = src[r * 256 + tid];
    __syncthreads();
    float s = 0.f;
#pragma unroll
    for (int t = 0; t < 9; ++t) {
      float v = wbuf[tid * 9 + t];
      s += v * v;
      wT[(long)p * 2304 + t * 256 + tid] = __float2bfloat16(v);
    }
    redw[tid] = s;
    __syncthreads();
    for (int off = 128; off > 0; off >>= 1) {
      if (tid < off) redw[tid] += redw[tid + off];
      __syncthreads();
    }
    if (tid == 0) ps[p] = redw[0];
  }
}

// ---------------- main kernel: ZERO-LDS register-streaming implicit GEMM ----------------
// C[p][pix] = sum_k wT[p][k]*xTpatch[pix][k]. Block tile 256x128, 4 waves (2M x 2N),
// wave-tile 128x64. Fragments loaded DIRECTLY global->VGPR (line-dense gathers):
// no LDS, no barriers, no vmcnt. B (L3-stream, long latency) register-double-buffered;
// A (L2-resident panel) loaded just-in-time. 2 waves/SIMD hide the rest.
__global__ __launch_bounds__(256, 2) void l2_main(
    const __hip_bfloat16* __restrict__ wT,   // [1024][2304]
    const __hip_bfloat16* __restrict__ xT,   // [32][784][256]
    const float* __restrict__ ps_sq,         // [1024]
    const float* __restrict__ sq,            // [32][784]
    float* __restrict__ out)                 // [32][1024][676]
{
  const int tid = threadIdx.x;
  const int wv = tid >> 6;
  const int lane = tid & 63;
  const int ln15 = lane & 15, kq = lane >> 4;
  const int wm = wv >> 1, wn = wv & 1;

  // T1: bijective XCD-chunk swizzle (676 = 4*85 + 4*84)
  const int bid = blockIdx.x;
  const int xcd = bid & 7, loc = bid >> 3;
  const int wg = (xcd < 4 ? xcd * 85 : 340 + (xcd - 4) * 84) + loc;
  const int py = wg / 169;
  const int nx = wg - py * 169;
  const int p0 = py << 8;      // proto base
  const int n0 = nx << 7;      // pixel base

  // A fragment source: row = p0 + wm*128 + i*16 + ln15, k-chunk = kq*8 + t*32
  const __hip_bfloat16* aSrc = wT + (long)(p0 + wm * 128 + ln15) * 2304 + kq * 8;

  // B fragment sources: pix = n0 + wn*64 + j*16 + ln15 (per-lane row base)
  const __hip_bfloat16* bSrc[4];
#pragma unroll
  for (int j = 0; j < 4; ++j) {
    int pix = n0 + wn * 64 + j * 16 + ln15;
    int b = pix / 676, e = pix - b * 676;
    int oh = e / 26, ow = e - oh * 26;
    bSrc[j] = xT + ((long)b * 784 + oh * 28 + ow) * 256 + kq * 8;
  }

  floatx4 acc[8][4];
#pragma unroll
  for (int i = 0; i < 8; ++i)
#pragma unroll
    for (int j = 0; j < 4; ++j) acc[i][j] = (floatx4){0.f, 0.f, 0.f, 0.f};

  auto loadB = [&](bf16x8 (&bq)[4], int t) {
    const int sl = t >> 3;                    // 0..8 (kh,kw) slice
    const int sh = (sl * 11) >> 5;            // sl/3
    const int off = (sh * 28 + (sl - 3 * sh)) * 256 + ((t & 7) << 5);
#pragma unroll
    for (int j = 0; j < 4; ++j)
      bq[j] = *(const bf16x8*)(bSrc[j] + off);
  };
  auto loadA = [&](bf16x8 (&af)[8], int t) {
    const int off = t << 5;                   // A k walks linearly
#pragma unroll
    for (int i = 0; i < 8; ++i)
      af[i] = *(const bf16x8*)(aSrc + i * 36864 + off);
  };
  auto mfmaStep = [&](bf16x8 (&af)[8], bf16x8 (&bq)[4]) {
    __builtin_amdgcn_s_setprio(1);
#pragma unroll
    for (int i = 0; i < 8; ++i)
#pragma unroll
      for (int j = 0; j < 4; ++j)
        acc[i][j] = __builtin_amdgcn_mfma_f32_16x16x32_bf16(af[i], bq[j], acc[i][j], 0, 0, 0);
    __builtin_amdgcn_s_setprio(0);
  };

  // 2-step pipeline, statically-named register buffers (rule 20)
  bf16x8 bqA[4], bqB[4];
  loadB(bqA, 0);
  for (int t = 0; t < 72; t += 2) {
    loadB(bqB, t + 1);
    {
      bf16x8 afA[8];
      loadA(afA, t);
      mfmaStep(afA, bqA);
    }
    if (t + 2 < 72) loadB(bqA, t + 2);
    {
      bf16x8 afB[8];
      loadA(afB, t + 1);
      mfmaStep(afB, bqB);
    }
  }

  // ---- epilogue: d = sqrt(max(box(sq) + ps - 2*acc, 1e-14))
  const int pixBase = n0 + wn * 64 + ln15;
  const int rowBase = p0 + wm * 128 + kq * 4;

#pragma unroll
  for (int j = 0; j < 4; ++j) {
    const int pix = pixBase + j * 16;
    const int b = pix / 676;
    const int pb = pix - b * 676;
    const int oh = pb / 26, ow = pb - oh * 26;
    const float* sp = sq + b * 784 + oh * 28 + ow;
    float xs = 0.f;
#pragma unroll
    for (int kh = 0; kh < 3; ++kh)
#pragma unroll
      for (int kw = 0; kw < 3; ++kw) xs += sp[kh * 28 + kw];
    float* op = out + (long)b * 692224 + pb;   // 676*1024
#pragma unroll
    for (int i = 0; i < 8; ++i) {
      const int p = rowBase + i * 16;
#pragma unroll
      for (int rr = 0; rr < 4; ++rr) {
        float d2 = xs + ps_sq[p + rr] - 2.0f * acc[i][j][rr];
        __builtin_nontemporal_store(sqrtf(fmaxf(d2, 1e-14f)), &op[(long)(p + rr) * 676]);
      }
    }
  }
}

// ---------------- launcher ----------------

extern "C" void kernel_launch(void* const* d_in, const int* in_sizes, int n_in,
                              void* d_out, int out_size, void* d_ws, size_t ws_size,
                              hipStream_t stream) {
  const float* x = (const float*)d_in[0];        // (32,256,28,28)
  const float* w = (const float*)d_in[1];        // (1024,256,3,3)
  float* out = (float*)d_out;                    // (32,1024,26,26)

  char* ws = (char*)d_ws;
  __hip_bfloat16* wT = (__hip_bfloat16*)ws;                       // 4,718,592 B
  __hip_bfloat16* xT = (__hip_bfloat16*)(ws + 4718592);           // 12,845,056 B
  float* ps = (float*)(ws + 17563648);                            // 4,096 B
  float* sq = (float*)(ws + 17567744);                            // 100,352 B

  prep_all<<<1536, 256, 0, stream>>>(x, w, xT, wT, ps, sq);
  l2_main<<<676, 256, 0, stream>>>(wT, xT, ps, sq, out);
}